// Round 8
// baseline (430.799 us; speedup 1.0000x reference)
//
#include <hip/hip_runtime.h>
#include <hip/hip_bf16.h>
#include <hip/hip_cooperative_groups.h>
#include <math.h>

namespace cg = cooperative_groups;

// ---------------------------------------------------------------------------
// B=1024, D_DATA=16384, D_LAT=256, N_GRID=256. Inputs f32.
// d_out = f32 slots; harness reads high u16 of each slot as bf16 (proven R6):
// store (float)__float2bfloat16(v).
//
// R8: Boruvka (10 rounds) + silhouette + final fused into ONE cooperative
// kernel (64 blk x 256 thr, 20 grid.sync) replacing 22 small launches that
// cost ~280 us in launch/latency overhead (R7 profile). deaths/cnt in block-0
// LDS; comp staged in LDS per block per round.
//
// ws layout (floats):
//   [0..4095]    recon/kl partials (2048+2048)
//   [4096..5119] sq (1024)
//   [5120..6143] comp (int[1024])
//   [6144..8191] minedge (u64[1024], byte 24576, 8-aligned)
//   [8192..]     dist 1024x1024 (4 MB)
// ---------------------------------------------------------------------------

#define NBLK 2048

__global__ __launch_bounds__(256) void losses_kernel(const float4* __restrict__ rx,
                                                     const float4* __restrict__ x,
                                                     const float4* __restrict__ mu,
                                                     const float4* __restrict__ lv,
                                                     const float* __restrict__ z,
                                                     float* __restrict__ partials,
                                                     float* __restrict__ sq) {
  const int t = threadIdx.x;
  const int gid = blockIdx.x * 256 + t;
  const int gstride = NBLK * 256;

  float rs = 0.f;
  for (int i = gid; i < 4194304; i += gstride) {   // 8 iterations
    float4 a = rx[i], b = x[i];
    float dx = a.x - b.x, dy = a.y - b.y, dz = a.z - b.z, dw = a.w - b.w;
    rs += dx * dx + dy * dy + dz * dz + dw * dw;
  }
  float ks = 0.f;
  if (gid < 65536) {
    float4 m = mu[gid], l = lv[gid];
    ks += 1.f + l.x - m.x * m.x - __expf(l.x);
    ks += 1.f + l.y - m.y * m.y - __expf(l.y);
    ks += 1.f + l.z - m.z * m.z - __expf(l.z);
    ks += 1.f + l.w - m.w * m.w - __expf(l.w);
  }
#pragma unroll
  for (int off = 32; off; off >>= 1) {
    rs += __shfl_xor(rs, off);
    ks += __shfl_xor(ks, off);
  }
  __shared__ float red[8];
  if ((t & 63) == 0) { red[t >> 6] = rs; red[4 + (t >> 6)] = ks; }
  __syncthreads();
  if (t == 0) {
    partials[blockIdx.x] = red[0] + red[1] + red[2] + red[3];
    partials[NBLK + blockIdx.x] = red[4] + red[5] + red[6] + red[7];
  }
  if (blockIdx.x < 256) {
    const int lane = t & 63;
    const int row = blockIdx.x * 4 + (t >> 6);
    float4 v = ((const float4*)(z + row * 256))[lane];
    float s = v.x * v.x + v.y * v.y + v.z * v.z + v.w * v.w;
#pragma unroll
    for (int off = 32; off; off >>= 1) s += __shfl_xor(s, off);
    if (lane == 0) sq[row] = s;
  }
}

__global__ __launch_bounds__(256) void dist_kernel(const float* __restrict__ z,
                                                   const float* __restrict__ sq,
                                                   float* __restrict__ dist,
                                                   int* __restrict__ comp) {
  if (blockIdx.x == 0 && blockIdx.y == 0) {
    for (int v = threadIdx.x; v < 1024; v += 256) comp[v] = v;
  }
  __shared__ float A[64][68];
  __shared__ float Bs[64][68];
  const int i0 = blockIdx.y * 64, j0 = blockIdx.x * 64;
  const int t = threadIdx.x;
  const int tx = t & 15;
  const int ty = t >> 4;
  float acc[4][4] = {};
  for (int k0 = 0; k0 < 256; k0 += 64) {
    __syncthreads();
#pragma unroll
    for (int it = 0; it < 4; ++it) {
      int lin = it * 256 + t;
      int row = lin >> 4, q = lin & 15;
      *(float4*)&A[row][q * 4]  = *(const float4*)(z + (i0 + row) * 256 + k0 + q * 4);
      *(float4*)&Bs[row][q * 4] = *(const float4*)(z + (j0 + row) * 256 + k0 + q * 4);
    }
    __syncthreads();
#pragma unroll 4
    for (int k = 0; k < 64; k += 4) {
      float4 av[4], bv[4];
#pragma unroll
      for (int rr = 0; rr < 4; ++rr) av[rr] = *(const float4*)&A[ty + 16 * rr][k];
#pragma unroll
      for (int cc = 0; cc < 4; ++cc) bv[cc] = *(const float4*)&Bs[tx + 16 * cc][k];
#pragma unroll
      for (int rr = 0; rr < 4; ++rr)
#pragma unroll
        for (int cc = 0; cc < 4; ++cc) {
          acc[rr][cc] += av[rr].x * bv[cc].x;
          acc[rr][cc] += av[rr].y * bv[cc].y;
          acc[rr][cc] += av[rr].z * bv[cc].z;
          acc[rr][cc] += av[rr].w * bv[cc].w;
        }
    }
  }
#pragma unroll
  for (int rr = 0; rr < 4; ++rr) {
    int i = i0 + ty + 16 * rr;
    float sqi = sq[i];
#pragma unroll
    for (int cc = 0; cc < 4; ++cc) {
      int j = j0 + tx + 16 * cc;
      float d2 = sqi + sq[j] - 2.f * acc[rr][cc];
      dist[i * 1024 + j] = sqrtf(fmaxf(d2, 0.f) + 1e-12f);
    }
  }
}

// Fused Boruvka (10 rounds) + silhouette + final. Cooperative, 64x256.
__global__ __launch_bounds__(256) void boruvka_fused(const float* __restrict__ dist,
                                                     int* __restrict__ comp,
                                                     unsigned long long* __restrict__ minedge,
                                                     const float* __restrict__ partials,
                                                     float* __restrict__ out) {
  cg::grid_group grid = cg::this_grid();
  const int t = threadIdx.x;
  const int blk = blockIdx.x;
  __shared__ int scomp[1024];
  __shared__ unsigned long long cmin[1024];
  __shared__ int pnew[1024];
  __shared__ float deaths[1024];
  __shared__ int cnt;
  __shared__ float red[8];
  __shared__ float red2[4];

  if (blk == 0 && t == 0) cnt = 0;

  for (int r = 0; r < 10; ++r) {
    for (int v = t; v < 1024; v += 256) scomp[v] = comp[v];
    __syncthreads();
    // ---- phase A: per-vertex min outgoing edge (16 rows per block) ----
    {
      const int wave = t >> 6, lane = t & 63;
#pragma unroll
      for (int rr = 0; rr < 4; ++rr) {
        const int i = blk * 16 + wave * 4 + rr;
        const int ci = scomp[i];
        const float4* row4 = (const float4*)(dist + i * 1024);
        unsigned long long best = ~0ull;
#pragma unroll
        for (int k = 0; k < 4; ++k) {
          float4 d4 = row4[lane + 64 * k];
          int jb = 4 * (lane + 64 * k);
          float dv[4] = {d4.x, d4.y, d4.z, d4.w};
#pragma unroll
          for (int c = 0; c < 4; ++c) {
            int j = jb + c;
            if (scomp[j] != ci) {
              int lo = i < j ? i : j, hi = i < j ? j : i;
              unsigned long long key = ((unsigned long long)__float_as_uint(dv[c]) << 32)
                                     | (unsigned long long)((lo << 10) | hi);
              best = key < best ? key : best;
            }
          }
        }
#pragma unroll
        for (int off = 32; off; off >>= 1) {
          unsigned int alo = __shfl_xor((unsigned int)best, off);
          unsigned int ahi = __shfl_xor((unsigned int)(best >> 32), off);
          unsigned long long o = ((unsigned long long)ahi << 32) | alo;
          best = o < best ? o : best;
        }
        if (lane == 0) minedge[i] = best;
      }
    }
    grid.sync();
    // ---- phase B: component min, record deaths, union + flatten (blk 0) ----
    if (blk == 0) {
      for (int v = t; v < 1024; v += 256) cmin[v] = ~0ull;
      __syncthreads();
      for (int v = t; v < 1024; v += 256) atomicMin(&cmin[scomp[v]], minedge[v]);
      __syncthreads();
      for (int v = t; v < 1024; v += 256) {
        int parent = scomp[v];
        if (parent == v) {                       // root
          unsigned long long key = cmin[v];
          if (key != ~0ull) {
            int lo = (int)((key >> 10) & 1023), hi = (int)(key & 1023);
            int clo = scomp[lo], chi = scomp[hi];
            int other = (clo == v) ? chi : clo;
            bool mutual = (cmin[other] == key);
            if (!mutual || v < other) {          // dedupe mutual pair
              int pos = atomicAdd(&cnt, 1);
              deaths[pos] = __uint_as_float((unsigned int)(key >> 32));
            }
            parent = (mutual && v < other) ? v : other;
          }
        }
        pnew[v] = parent;
      }
      __syncthreads();
      for (int it = 0; it < 10; ++it) {
        int p[4];
#pragma unroll
        for (int k = 0; k < 4; ++k) p[k] = pnew[pnew[t + 256 * k]];
        __syncthreads();
#pragma unroll
        for (int k = 0; k < 4; ++k) pnew[t + 256 * k] = p[k];
        __syncthreads();
      }
      for (int v = t; v < 1024; v += 256) comp[v] = pnew[v];
    }
    grid.sync();
  }

  // ---- silhouette + final combine (block 0 only; deaths in LDS) ----
  if (blk != 0) return;
  float lmax = 0.f, lsum = 0.f;
  for (int i = t; i < 1023; i += 256) {
    float v = deaths[i];
    lmax = fmaxf(lmax, v);
    lsum += v;
  }
#pragma unroll
  for (int off = 32; off; off >>= 1) {
    lmax = fmaxf(lmax, __shfl_xor(lmax, off));
    lsum += __shfl_xor(lsum, off);
  }
  if ((t & 63) == 0) { red[t >> 6] = lmax; red[4 + (t >> 6)] = lsum; }
  __syncthreads();
  float tmax = fmaxf(fmaxf(red[0], red[1]), fmaxf(red[2], red[3]));
  float wsum = red[4] + red[5] + red[6] + red[7];
  float tt = (float)t * (1.0f / 255.0f) * tmax;
  float acc = 0.f;
  for (int j = 0; j < 1023; ++j) {
    float dj = deaths[j];
    acc += dj * fmaxf(fminf(tt, dj - tt), 0.f);
  }
  float phi = acc / (wsum + 1e-12f);
#pragma unroll
  for (int off = 32; off; off >>= 1) phi += __shfl_xor(phi, off);
  if ((t & 63) == 0) red2[t >> 6] = phi;
  __syncthreads();
  if (t == 0) red2[0] = (red2[0] + red2[1] + red2[2] + red2[3]) * (1.f / 256.f);
  __syncthreads();
  float topo = red2[0];

  float rs = 0.f, ks = 0.f;
  for (int i = t; i < NBLK; i += 256) { rs += partials[i]; ks += partials[NBLK + i]; }
#pragma unroll
  for (int off = 32; off; off >>= 1) {
    rs += __shfl_xor(rs, off);
    ks += __shfl_xor(ks, off);
  }
  if ((t & 63) == 0) { red[t >> 6] = rs; red[4 + (t >> 6)] = ks; }
  __syncthreads();
  if (t == 0) {
    float recon = (red[0] + red[1] + red[2] + red[3]) * (1.f / 16777216.f);
    float kl = -0.5f * (red[4] + red[5] + red[6] + red[7]) * (1.f / 262144.f);
    float total = recon + 0.1f * kl + 0.5f * topo;
    out[0] = (float)__float2bfloat16(total);
    out[1] = (float)__float2bfloat16(recon);
    out[2] = (float)__float2bfloat16(kl);
    out[3] = (float)__float2bfloat16(topo);
  }
}

extern "C" void kernel_launch(void* const* d_in, const int* in_sizes, int n_in,
                              void* d_out, int out_size, void* d_ws, size_t ws_size,
                              hipStream_t stream) {
  const float* rx = (const float*)d_in[0];
  const float* x  = (const float*)d_in[1];
  const float* mu = (const float*)d_in[2];
  const float* lv = (const float*)d_in[3];
  const float* z  = (const float*)d_in[4];

  float* wsf = (float*)d_ws;
  float* partials = wsf;                                   // [0..4095]
  float* sq       = wsf + 4096;
  int*   comp     = (int*)(wsf + 5120);
  unsigned long long* minedge = (unsigned long long*)(wsf + 6144);
  float* dist     = wsf + 8192;
  float* out      = (float*)d_out;

  losses_kernel<<<NBLK, 256, 0, stream>>>((const float4*)rx, (const float4*)x,
                                          (const float4*)mu, (const float4*)lv,
                                          z, partials, sq);
  dist_kernel<<<dim3(16, 16), 256, 0, stream>>>(z, sq, dist, comp);

  void* args[] = {(void*)&dist, (void*)&comp, (void*)&minedge,
                  (void*)&partials, (void*)&out};
  hipLaunchCooperativeKernel((void*)boruvka_fused, dim3(64), dim3(256),
                             args, 0, stream);
}